// Round 10
// baseline (57.471 us; speedup 1.0000x reference)
//
#include <hip/hip_runtime.h>
#include <math.h>

// GraphGenerator: radius-graph adjacency, OR over {0,0.25,0.5,0.75}*domain
// wrapped shifts, diagonal excluded. Output [N,N] int32 0/1.
//
// Golden ("ref=np") — PROVEN in R7 (absmax 0):
//   sq   = ((x*x) + (y*y)) + (z*z)          separately rounded (contract off!)
//   dot  = fma(z,z', fma(y,y', rn(x*x')))   sgemm sequential-k FMA chain
//   d2   = rn(rn(sq_i + sq_j) - rn(2*dot))
//   pred = d2 <= 0.01f ; wrap = fmodf(rn(x + rn(f*d)), d)
//
// Min-image prefilter (R8-proven): min-image d2 lower-bounds all variants and
// is achieved by one of them (seam argument); fast/golden chains differ by
// < 3e-5 worst case, so outside the +-3e-5 band the fast f32 decision is
// identical to the golden OR. In-band groups recompute the exact R7 chain.

typedef int iv4 __attribute__((ext_vector_type(4)));  // native vec for NT store

__global__ __launch_bounds__(256) void gg_shift_kernel(
    const float* __restrict__ pos, const float* __restrict__ dom,
    float4* __restrict__ sp, int n)
{
#pragma clang fp contract(off)
    int i = blockIdx.x * blockDim.x + threadIdx.x;
    if (i >= n) return;
    float x = pos[3 * i + 0];
    float y = pos[3 * i + 1];
    float z = pos[3 * i + 2];
    float dx = dom[0], dy = dom[1], dz = dom[2];
#pragma unroll
    for (int k = 0; k < 4; ++k) {
        float sx, sy, sz;
        if (k == 0) {
            sx = x; sy = y; sz = z;
        } else {
            float f = 0.25f * (float)k;
            sx = fmodf(x + f * dx, dx);
            sy = fmodf(y + f * dy, dy);
            sz = fmodf(z + f * dz, dz);
        }
        float sq = ((sx * sx) + (sy * sy)) + (sz * sz);
        sp[(size_t)i * 4 + k] = make_float4(sx, sy, sz, sq);
    }
}

// Tile: 32 i-rows x 256 j-cols per 256-thread block.
__global__ __launch_bounds__(256) void gg_adj_kernel(
    const float4* __restrict__ sp, const float* __restrict__ dom,
    int* __restrict__ out, int n)
{
    const int tid = threadIdx.x;
    const int tj = tid & 63;
    const int ti = tid >> 6;
    const int jbase = blockIdx.x * 256 + tj * 4;
    const int ibase = blockIdx.y * 32;
    // Diagonal can only appear when this i-stripe lies in this j-panel.
    const bool hasdiag = ((blockIdx.y >> 3) == blockIdx.x);

    const float dom0 = dom[0], dom1 = dom[1], dom2 = dom[2];

    __shared__ float4 si[32][4];   // i-tile: 4 variants (slow path needs all)
    for (int t = tid; t < 128; t += 256)
        si[t >> 2][t & 3] = sp[(size_t)(ibase + (t >> 2)) * 4 + (t & 3)];

    float4 jd0[4];                 // j-side raw coords (variant 0)
#pragma unroll
    for (int p = 0; p < 4; ++p)
        jd0[p] = sp[(size_t)(jbase + p) * 4 + 0];

    __syncthreads();

    const float RR  = 0.01f;       // f32(0.1*0.1)
    const float EPS = 3e-5f;       // band half-width

    for (int iter = 0; iter < 8; ++iter) {
        const int irow = iter * 4 + ti;
        const int i = ibase + irow;
        const float4 i0 = si[irow][0];       // LDS broadcast, raw coords

        float d2m[4];
#pragma unroll
        for (int p = 0; p < 4; ++p) {
            const float dxv = i0.x - jd0[p].x;
            const float dyv = i0.y - jd0[p].y;
            const float dzv = i0.z - jd0[p].z;
            const float mx = fminf(fabsf(dxv), dom0 - fabsf(dxv));
            const float my = fminf(fabsf(dyv), dom1 - fabsf(dyv));
            const float mz = fminf(fabsf(dzv), dom2 - fabsf(dzv));
            d2m[p] = mx * mx + my * my + mz * mz;   // contraction fine
        }

        bool b0 = d2m[0] <= RR, b1 = d2m[1] <= RR,
             b2 = d2m[2] <= RR, b3 = d2m[3] <= RR;

        const bool band = (fabsf(d2m[0] - RR) <= EPS) |
                          (fabsf(d2m[1] - RR) <= EPS) |
                          (fabsf(d2m[2] - RR) <= EPS) |
                          (fabsf(d2m[3] - RR) <= EPS);
        if (__builtin_expect(band, 0)) {
            // Rare: recompute ALL 4 pairs with the exact R7 golden chain.
#pragma clang fp contract(off)
            bool bb[4] = {false, false, false, false};
#pragma unroll 1
            for (int k = 0; k < 4; ++k) {
                const float4 iv = si[irow][k];
#pragma unroll
                for (int p = 0; p < 4; ++p) {
                    const float4 jv = sp[(size_t)(jbase + p) * 4 + k];
                    float dot = __builtin_fmaf(iv.z, jv.z,
                                __builtin_fmaf(iv.y, jv.y, iv.x * jv.x));
                    float d2 = (iv.w + jv.w) - (2.0f * dot);
                    if (d2 <= RR) bb[p] = true;
                }
            }
            b0 = bb[0]; b1 = bb[1]; b2 = bb[2]; b3 = bb[3];
        }

        iv4 res;
        res.x = b0 ? 1 : 0;
        res.y = b1 ? 1 : 0;
        res.z = b2 ? 1 : 0;
        res.w = b3 ? 1 : 0;
        if (hasdiag) {
            if (i == jbase + 0) res.x = 0;
            if (i == jbase + 1) res.y = 0;
            if (i == jbase + 2) res.z = 0;
            if (i == jbase + 3) res.w = 0;
        }
        __builtin_nontemporal_store(
            res, reinterpret_cast<iv4*>(&out[(size_t)i * n + jbase]));
    }
}

extern "C" void kernel_launch(void* const* d_in, const int* in_sizes, int n_in,
                              void* d_out, int out_size, void* d_ws, size_t ws_size,
                              hipStream_t stream) {
    const float* pos = (const float*)d_in[0];   // [N,3] float32
    const float* dom = (const float*)d_in[1];   // [3] float32
    const int n = in_sizes[0] / 3;              // 8192

    float4* sp = (float4*)d_ws;                 // [N][4] float4 = 512 KB
    int* out = (int*)d_out;                     // [N,N] int32 0/1

    gg_shift_kernel<<<(n + 255) / 256, 256, 0, stream>>>(pos, dom, sp, n);

    dim3 grid(n / 256, n / 32);                 // (32, 256)
    gg_adj_kernel<<<grid, 256, 0, stream>>>(sp, dom, out, n);
}